// Round 3
// baseline (659.558 us; speedup 1.0000x reference)
//
#include <hip/hip_runtime.h>
#include <stdint.h>

// Problem constants (B=8192, N=8, H=256)
#define BB 8192
#define HH 256
#define HO 128            // H/2
#define NODES 24          // 3N
#define EPER 90
// Output layout (float32 elements, concatenated in return order)
#define NF_SIZE (BB * NODES * HH)
#define EI_OFF  NF_SIZE
#define EI_SIZE (2 * BB * EPER)
#define EA_OFF  (EI_OFF + EI_SIZE)
#define EA_SIZE (BB * EPER * 16)
#define BV_OFF  (EA_OFF + EA_SIZE)

typedef float f4 __attribute__((ext_vector_type(4)));

// Scalar load of one node-row float4: dst <- mem[base + IMM].
// Wave-uniform address -> SMEM path; data lands in SGPRs, broadcast to the
// VALU for free as the 1-SGPR operand of v_fma.
#define SL(dst, base, IMM) \
    asm volatile("s_load_dwordx4 %0, %1, " IMM : "=s"(dst) : "s"(base))

// Full-drain wait (SMEM may return out of order -> only lgkmcnt(0) is safe),
// with the 8 buffers tied as "+s" so the compiler cannot hoist their uses
// above the wait (rule 18: data dependency, not just volatile ordering).
#define SWAIT8(a0,a1,a2,a3,a4,a5,a6,a7) \
    asm volatile("s_waitcnt lgkmcnt(0)" \
                 : "+s"(a0),"+s"(a1),"+s"(a2),"+s"(a3), \
                   "+s"(a4),"+s"(a5),"+s"(a6),"+s"(a7))

// NOTE: parameter names must not collide with vector component names after
// the '.' token (round-2 failure: param `x` expanded `.x` -> `.x0`).
// Use [] indexing on ext_vector_type instead.
#define FMA4(acc, W_, X_) \
    acc = fmaf((W_)[0],(X_)[0],acc); acc = fmaf((W_)[1],(X_)[1],acc); \
    acc = fmaf((W_)[2],(X_)[2],acc); acc = fmaf((W_)[3],(X_)[3],acc);

// Load 8 node rows (1024B row stride) of one sample's kk-column into SGPRs.
#define LD8(BUF, ADDR) \
    SL(BUF##0, ADDR, "0x0");    SL(BUF##1, ADDR, "0x400"); \
    SL(BUF##2, ADDR, "0x800");  SL(BUF##3, ADDR, "0xc00"); \
    SL(BUF##4, ADDR, "0x1000"); SL(BUF##5, ADDR, "0x1400"); \
    SL(BUF##6, ADDR, "0x1800"); SL(BUF##7, ADDR, "0x1c00");

// 64 FMAs: 8 nodes x 2 W-row-halves x 4 components.
#define C8(ACC0, ACC1, BUF) \
    FMA4(ACC0[0], w0, BUF##0) FMA4(ACC1[0], w1, BUF##0) \
    FMA4(ACC0[1], w0, BUF##1) FMA4(ACC1[1], w1, BUF##1) \
    FMA4(ACC0[2], w0, BUF##2) FMA4(ACC1[2], w1, BUF##2) \
    FMA4(ACC0[3], w0, BUF##3) FMA4(ACC1[3], w1, BUF##3) \
    FMA4(ACC0[4], w0, BUF##4) FMA4(ACC1[4], w1, BUF##4) \
    FMA4(ACC0[5], w0, BUF##5) FMA4(ACC1[5], w1, BUF##5) \
    FMA4(ACC0[6], w0, BUF##6) FMA4(ACC1[6], w1, BUF##6) \
    FMA4(ACC0[7], w0, BUF##7) FMA4(ACC1[7], w1, BUF##7)

// ---------------------------------------------------------------------------
// Pre-pass: W2T[kk][o] = float4(W[o][4kk..4kk+3]) for Wq then Wk (round-1 win:
// coalesced per-lane W stream). One-time 256 KB shuffle into d_ws.
// ---------------------------------------------------------------------------
__global__ __launch_bounds__(256) void transpose_w(
    const float4* __restrict__ Wq4, const float4* __restrict__ Wk4,
    float4* __restrict__ ws)
{
    int idx = blockIdx.x * 256 + threadIdx.x;   // 0..16383
    const float4* src = (idx < 8192) ? Wq4 : Wk4;
    int j  = idx & 8191;
    int o  = j >> 6;          // row 0..127
    int kk = j & 63;          // h-chunk 0..63
    float4 v = src[j];
    ws[(idx & 8192) + kk * 128 + o] = v;
}

// ---------------------------------------------------------------------------
// Main kernel: S=2 samples per block. x streamed through SGPRs (no LDS
// broadcast), W streamed per-lane from the transposed workspace and reused
// across both samples (halves W L2 traffic).
// ---------------------------------------------------------------------------
__global__ __launch_bounds__(256) void htdg_kernel(
    const float* __restrict__ zt, const float* __restrict__ za,
    const float* __restrict__ zf,
    const float* __restrict__ bq, const float* __restrict__ bk,
    const float* __restrict__ emb, const float* __restrict__ wt,
    float* __restrict__ out)
{
    __shared__ float uv[2 * 32 * HO];      // 32 KB: [sample][slot][o]
    __shared__ float nrm_part[2][256];
    __shared__ float dot_part[2][192];
    __shared__ float rnorm_s[2][32];
    __shared__ float disc_s[2][24];
    __shared__ int   et_s[2][24];
    __shared__ float emb_s[40];

    const int b0  = blockIdx.x * 2;
    const int tid = threadIdx.x;

    // ---- Phase 0: node_feats copy for both samples (pure global->global) ----
    {
        const f4* zt4 = (const f4*)zt + (size_t)b0 * 512;   // 512 f4 per sample
        const f4* za4 = (const f4*)za + (size_t)b0 * 512;
        const f4* zf4 = (const f4*)zf + (size_t)b0 * 512;
        f4* nf = (f4*)out + (size_t)b0 * 1536;
        #pragma unroll
        for (int it = 0; it < 12; ++it) {
            int j = tid + it * 256;          // 0..3071 float4s (2 samples)
            int s = (it >= 6);               // compile-time per it
            int rem = j - s * 1536;
            int m = rem >> 9, w = rem & 511;
            const f4* sp = (m == 0 ? zt4 : m == 1 ? za4 : zf4) + s * 512 + w;
            nf[j] = *sp;
        }
        if (tid < 40) emb_s[tid] = emb[tid];
    }

    // ---- edge_index + batch_vec for both samples ----
    #pragma unroll
    for (int s = 0; s < 2; ++s) {
        int b = b0 + s;
        int j = tid;
        if (j < 180) {
            int d = (j >= 90) ? 1 : 0;
            int e = j - d * 90;
            int ss, dd;
            if (e < 42) {
                int m = e / 14;
                int r = e - m * 14;
                int i = r >> 1;
                int u = m * 8 + i;
                if (r & 1) { ss = u + 1; dd = u; } else { ss = u; dd = u + 1; }
            } else {
                int p  = (e - 42) >> 1;
                int pr = p >> 3;
                int i  = p & 7;
                int a  = (pr == 2 ? 8 : 0) + i;
                int bb = (pr == 0 ? 8 : 16) + i;
                if (e & 1) { ss = bb; dd = a; } else { ss = a; dd = bb; }
            }
            int val = ((d == 0) ? ss : dd) + b * 24;
            out[(size_t)EI_OFF + (size_t)d * (BB * EPER) + (size_t)b * EPER + e] = (float)val;
        }
        if (tid < 24) out[(size_t)BV_OFF + (size_t)b * 24 + tid] = (float)b;
    }

    // ---- Phase 1: matvec, x via SGPRs (SMEM), W via coalesced VGPR stream ----
    // wave0: Q rows for nodes 0-7 (zt); wave1: Q nodes 8-15 (za);
    // wave2: K nodes 8-15 (za);        wave3: K nodes 16-23 (zf).
    // All waves use modality-local rows 0..7 -> identical byte offsets.
    {
        const int wave = tid >> 6;
        const int lane = tid & 63;
        const f4* Wt4 = (const f4*)wt + ((wave < 2) ? 0 : 8192);
        const float* zsel = (wave == 0) ? zt : (wave == 3) ? zf : za;
        const float* bias = (wave < 2) ? bq : bk;
        const int slotBase = wave * 8;

        uint64_t xb;
        {   // wave-uniform base -> SGPR pair (explicit readfirstlane)
            // sample stride = 8 rows * 256 f32 = 8192 bytes
            uint64_t v = (uint64_t)zsel + (uint64_t)b0 * 8192;
            uint32_t lo = __builtin_amdgcn_readfirstlane((uint32_t)v);
            uint32_t hi = __builtin_amdgcn_readfirstlane((uint32_t)(v >> 32));
            xb = ((uint64_t)hi << 32) | lo;
        }

        float A0r0[8] = {0,0,0,0,0,0,0,0}, A0r1[8] = {0,0,0,0,0,0,0,0};
        float A1r0[8] = {0,0,0,0,0,0,0,0}, A1r1[8] = {0,0,0,0,0,0,0,0};
        f4 x0, x1, x2, x3, x4, x5, x6, x7;      // sample-0 column buffer
        f4 y0, y1, y2, y3, y4, y5, y6, y7;      // sample-1 column buffer

        f4 w0 = Wt4[lane];
        f4 w1 = Wt4[64 + lane];

        LD8(x, xb);                              // prologue: (kk=0, s=0)

        for (int kk = 0; kk < 64; ++kk) {
            int kn = (kk < 63) ? kk + 1 : 63;          // clamp (no OOB)
            f4 nw0 = Wt4[kn * 128 + lane];             // W prefetch (VMEM)
            f4 nw1 = Wt4[kn * 128 + 64 + lane];
            uint64_t aB = xb + (uint64_t)(8192 + kk * 16);  // (kk,   s=1)
            uint64_t aA = xb + (uint64_t)(kn * 16);         // (kk+1, s=0)

            SWAIT8(x0, x1, x2, x3, x4, x5, x6, x7);    // s0 column ready
            LD8(y, aB);                                // issue s1 column
            C8(A0r0, A0r1, x);                         // 64 fmas (covers y)

            SWAIT8(y0, y1, y2, y3, y4, y5, y6, y7);    // s1 column ready
            LD8(x, aA);                                // issue next-kk s0
            C8(A1r0, A1r1, y);                         // 64 fmas (covers x)

            w0 = nw0; w1 = nw1;
        }
        asm volatile("s_waitcnt lgkmcnt(0)");          // drain final issues

        float bb0 = bias[lane], bb1 = bias[lane + 64];
        #pragma unroll
        for (int n = 0; n < 8; ++n) {
            uv[(slotBase + n) * HO + lane]             = A0r0[n] + bb0;
            uv[(slotBase + n) * HO + 64 + lane]        = A0r1[n] + bb1;
            uv[4096 + (slotBase + n) * HO + lane]      = A1r0[n] + bb0;
            uv[4096 + (slotBase + n) * HO + 64 + lane] = A1r1[n] + bb1;
        }
    }
    __syncthreads();

    // ---- Phase 2: norms and pair-dot partials, both samples ----
    #pragma unroll
    for (int s = 0; s < 2; ++s) {
        const float* uvS = uv + s * 4096;
        {
            int slot = tid >> 3, part = tid & 7;
            const float* u = &uvS[slot * HO + part * 16];
            float sum = 0.f;
            #pragma unroll
            for (int o = 0; o < 16; ++o) { float v = u[o]; sum += v * v; }
            nrm_part[s][tid] = sum;
        }
        if (tid < 192) {
            int p = tid >> 3, part = tid & 7;
            int pr = p >> 3, i = p & 7;
            int aslot = (pr == 2 ? 8 : 0) + i;
            int bslot = (pr == 0 ? 16 : 24) + i;
            const float* ua = &uvS[aslot * HO + part * 16];
            const float* vb = &uvS[bslot * HO + part * 16];
            float sum = 0.f;
            #pragma unroll
            for (int o = 0; o < 16; ++o) sum += ua[o] * vb[o];
            dot_part[s][tid] = sum;
        }
    }
    __syncthreads();
    if (tid < 64) {
        int s = tid >> 5, sl = tid & 31;
        float sum = 0.f;
        #pragma unroll
        for (int j = 0; j < 8; ++j) sum += nrm_part[s][sl * 8 + j];
        rnorm_s[s][sl] = 1.0f / fmaxf(sqrtf(sum), 1e-12f);
    }
    __syncthreads();
    if (tid < 64) {
        int s = tid >> 5, p = tid & 31;
        if (p < 24) {
            float sum = 0.f;
            #pragma unroll
            for (int j = 0; j < 8; ++j) sum += dot_part[s][p * 8 + j];
            int pr = p >> 3, i = p & 7;
            int aslot = (pr == 2 ? 8 : 0) + i;
            int bslot = (pr == 0 ? 16 : 24) + i;
            float t   = sum * rnorm_s[s][aslot] * rnorm_s[s][bslot];
            float dsc = 1.0f / (1.0f + expf(t));   // 1 - sigmoid(t)
            disc_s[s][p] = dsc;
            et_s[s][p]   = (dsc > 0.4f) ? 4 : 3;
        }
    }
    __syncthreads();

    // ---- Phase 3: edge_attr, both samples ----
    #pragma unroll
    for (int s = 0; s < 2; ++s) {
        float* ea = out + (size_t)EA_OFF + (size_t)(b0 + s) * (EPER * 16);
        #pragma unroll
        for (int it = 0; it < 6; ++it) {
            int j = tid + it * 256;
            if (j < 1440) {
                int row = j >> 4, c = j & 15;
                float val;
                if (row < 42) {
                    int m = row / 14;
                    if      (c < 8)   val = emb_s[m * 8 + c];
                    else if (c == 9)  val = 0.125f;
                    else if (c == 10) val = 1.0f;
                    else if (c == 11) val = (float)m * 0.25f;
                    else              val = 0.0f;
                } else {
                    int p  = (row - 42) >> 1;
                    int et = et_s[s][p];
                    if      (c < 8)   val = emb_s[et * 8 + c];
                    else if (c == 8)  val = disc_s[s][p];
                    else if (c == 11) val = (float)et * 0.25f;
                    else              val = 0.0f;
                }
                ea[j] = val;
            }
        }
    }
}

extern "C" void kernel_launch(void* const* d_in, const int* in_sizes, int n_in,
                              void* d_out, int out_size, void* d_ws, size_t ws_size,
                              hipStream_t stream) {
    const float* zt  = (const float*)d_in[0];
    const float* za  = (const float*)d_in[1];
    const float* zf  = (const float*)d_in[2];
    const float* Wq  = (const float*)d_in[3];
    const float* bq  = (const float*)d_in[4];
    const float* Wk  = (const float*)d_in[5];
    const float* bk  = (const float*)d_in[6];
    const float* emb = (const float*)d_in[7];

    float4* ws = (float4*)d_ws;
    transpose_w<<<64, 256, 0, stream>>>((const float4*)Wq, (const float4*)Wk, ws);
    htdg_kernel<<<BB / 2, 256, 0, stream>>>(zt, za, zf, bq, bk, emb,
                                            (const float*)ws, (float*)d_out);
}